// Round 10
// baseline (652.229 us; speedup 1.0000x reference)
//
#include <hip/hip_runtime.h>

typedef unsigned short ushort;
typedef unsigned int uint;
typedef __bf16 bf16x8 __attribute__((ext_vector_type(8)));
typedef unsigned short u16x8 __attribute__((ext_vector_type(8)));
typedef float f32x4 __attribute__((ext_vector_type(4)));

__device__ __forceinline__ ushort f2bf(float f) {
  uint u = __builtin_bit_cast(uint, f);
  u += 0x7fffu + ((u >> 16) & 1u);
  return (ushort)(u >> 16);
}

__device__ __forceinline__ f32x4 mfma_bf16(u16x8 a, u16x8 b, f32x4 c) {
  return __builtin_amdgcn_mfma_f32_16x16x32_bf16(
      __builtin_bit_cast(bf16x8, a), __builtin_bit_cast(bf16x8, b), c, 0, 0, 0);
}

// window-ordered row -> original token row (B=32, H=W=56, ws=7)
__device__ __forceinline__ uint win2orig(uint wr) {
  uint b = wr / 3136u, rem = wr % 3136u;
  uint g = rem / 49u, s = rem % 49u;
  return b * 3136u + ((g >> 3) * 7u + s / 7u) * 56u + (g & 7u) * 7u + s % 7u;
}

// x fp32 (orig order) -> xb bf16 (window order), 8 elems/thread
__global__ __launch_bounds__(256) void cvt_x_win(const float* __restrict__ X,
                                                 ushort* __restrict__ Xb, int total8) {
  int stride = gridDim.x * 256;
  for (int i = blockIdx.x * 256 + threadIdx.x; i < total8; i += stride) {
    uint wr = (uint)i >> 6, c8 = (uint)i & 63u;
    const float* xp = X + (size_t)win2orig(wr) * 512 + c8 * 8;
    f32x4 a = *(const f32x4*)xp;
    f32x4 b = *(const f32x4*)(xp + 4);
    u16x8 o;
#pragma unroll
    for (int j = 0; j < 4; ++j) { o[j] = f2bf(a[j]); o[j + 4] = f2bf(b[j]); }
    ((u16x8*)Xb)[i] = o;
  }
}

// W[K][N] fp32 -> WT[N][K] bf16, LDS-tiled 32x32
__global__ __launch_bounds__(256) void transpose_cvt(const float* __restrict__ W,
                                                     ushort* __restrict__ WT,
                                                     int K, int N) {
  __shared__ float t[32][33];
  const int tn0 = blockIdx.x * 32, tk0 = blockIdx.y * 32;
  const int tx = threadIdx.x & 31, ty = threadIdx.x >> 5;
#pragma unroll
  for (int i = 0; i < 4; ++i) {
    int k = tk0 + ty + i * 8;
    t[ty + i * 8][tx] = W[(size_t)k * N + tn0 + tx];
  }
  __syncthreads();
#pragma unroll
  for (int i = 0; i < 4; ++i) {
    int n = tn0 + ty + i * 8;
    WT[(size_t)n * K + tk0 + tx] = f2bf(t[tx][ty + i * 8]);
  }
}

// ---- 128x128 GEMM, K=512: A via 3-buf LDS (48 KB, 2-deep prefetch),
// B direct from L2, double-banked in regs (1-deep prefetch). 4 waves,
// one barrier per K-step; 3 blocks/CU TLP fills the rest.
// vmcnt ledger (per wave, SCB-pinned issue order per iter:
//   STAGE(kt+2) [4 GLL] -> LOADBF(kt+1) [8 loads] -> MFMA(kt)):
// the compiler's mandatory pre-MFMA(kt) wait for bf(kt)'s registers
// (issued AFTER stage(kt+1) last iter) drains stage(kt+1) in FIFO order
// -> stage(kt+1) is complete before BAR(kt+1) with no explicit drain.
// WAR: stage(kt+2) overwrites buf[(kt+2)%3]; its last reads (iter kt-1)
// were lgkm-drained before MFMA(kt-1) < BAR(kt) < stage(kt+2). Safe.

#define GLL(g, l)                                                              \
  __builtin_amdgcn_global_load_lds(                                            \
      (const __attribute__((address_space(1))) uint*)(g),                      \
      (__attribute__((address_space(3))) uint*)(l), 16, 0, 0)
#define BAR() __builtin_amdgcn_s_barrier()
#define SCB() __builtin_amdgcn_sched_barrier(0)
#define WAITV(n) asm volatile("s_waitcnt vmcnt(" #n ")" ::: "memory")

template <int OUT>
__global__ __launch_bounds__(256, 3) void gemm_bl2(const ushort* __restrict__ A,
                                                   const ushort* __restrict__ BT,
                                                   void* __restrict__ Cout,
                                                   const float* __restrict__ bias,
                                                   const int ldc, const int NT,
                                                   const int CPX) {
  __shared__ __align__(16) ushort as_[3][8192];  // 3 x (128 x 64) bf16 = 48 KB
  const int bid = blockIdx.x;
  const int wg = (bid & 7) * CPX + (bid >> 3);  // XCD swizzle (grid % 8 == 0)
  const int mt = wg / NT, nt = wg - mt * NT;    // ntile-inner: B L2-resident
  const int m0 = mt << 7, n0 = nt << 7;
  const int tid = threadIdx.x, lane = tid & 63, wid = tid >> 6;
  const int wm = wid >> 1, wn = wid & 1;
  const int c16 = lane & 15, q4 = lane >> 4;
  const int sw = c16 & 7;

  // A staging source: thread t covers LDS slot (row=t>>3, gs=t&7); source
  // granule is gs ^ (row&7) so the read-side XOR recovers linear k.
  const ushort* Ag = A + (size_t)(m0 + (tid >> 3)) * 512 +
                     ((tid & 7) ^ ((tid >> 3) & 7)) * 8;
  // B-fragment bases: 4 col-rows per lane (direct global; L2-resident)
  const ushort* Bg0 = BT + (size_t)(n0 + wn * 64 + c16) * 512 + q4 * 8;
  const ushort* Bg1 = Bg0 + (size_t)16 * 512;
  const ushort* Bg2 = Bg0 + (size_t)32 * 512;
  const ushort* Bg3 = Bg0 + (size_t)48 * 512;

  const int aro = wm * 64 + c16;         // af row base (+ f*16)
  const int ag0 = (q4 ^ sw) * 8;         // kk=0 granule slot
  const int ag1 = ((4 + q4) ^ sw) * 8;   // kk=1

  f32x4 acc[4][4];
#pragma unroll
  for (int m = 0; m < 4; ++m)
#pragma unroll
    for (int n = 0; n < 4; ++n) acc[m][n] = f32x4{0.f, 0.f, 0.f, 0.f};

  u16x8 bfr[2][2][4];  // [bank][kk][n]

#define STAGE(buf, ktg)                                                        \
  do {                                                                         \
    _Pragma("unroll") for (int j_ = 0; j_ < 4; ++j_)                           \
        GLL(Ag + (size_t)j_ * (32 * 512) + (ktg)*64,                           \
            &as_[buf][j_ * 2048 + tid * 8]);                                   \
  } while (0)
#define LOADBF(bank, ktg)                                                      \
  do {                                                                         \
    _Pragma("unroll") for (int kk_ = 0; kk_ < 2; ++kk_) {                      \
      bfr[bank][kk_][0] = *(const u16x8*)(Bg0 + (ktg)*64 + kk_ * 32);          \
      bfr[bank][kk_][1] = *(const u16x8*)(Bg1 + (ktg)*64 + kk_ * 32);          \
      bfr[bank][kk_][2] = *(const u16x8*)(Bg2 + (ktg)*64 + kk_ * 32);          \
      bfr[bank][kk_][3] = *(const u16x8*)(Bg3 + (ktg)*64 + kk_ * 32);          \
    }                                                                          \
  } while (0)

  // Prologue: A(0)->buf0, A(1)->buf1, bf(0)->bank0.
  STAGE(0, 0);
  SCB();
  LOADBF(0, 0);
  SCB();
  STAGE(1, 1);
  WAITV(12);  // outstanding 16: drain stage(0) (oldest 4)

#pragma unroll
  for (int kt = 0; kt < 8; ++kt) {
    BAR();
    SCB();
    if (kt < 6) STAGE((kt + 2) % 3, kt + 2);
    SCB();  // pin: stage(kt+2) issues before bf(kt+1)
    if (kt < 7) LOADBF((kt + 1) & 1, kt + 1);
    SCB();  // pin: bf loads issue before af ds_reads / MFMA
    const ushort* ab = &as_[kt % 3][0];
    u16x8 af0[4];
#pragma unroll
    for (int f = 0; f < 4; ++f)
      af0[f] = *(const u16x8*)(ab + (aro + f * 16) * 64 + ag0);
    __builtin_amdgcn_s_setprio(1);
#pragma unroll
    for (int m = 0; m < 4; ++m)
#pragma unroll
      for (int n = 0; n < 4; ++n)
        acc[m][n] = mfma_bf16(af0[m], bfr[kt & 1][0][n], acc[m][n]);
    __builtin_amdgcn_s_setprio(0);
    u16x8 af1[4];
#pragma unroll
    for (int f = 0; f < 4; ++f)
      af1[f] = *(const u16x8*)(ab + (aro + f * 16) * 64 + ag1);
    __builtin_amdgcn_s_setprio(1);
#pragma unroll
    for (int m = 0; m < 4; ++m)
#pragma unroll
      for (int n = 0; n < 4; ++n)
        acc[m][n] = mfma_bf16(af1[m], bfr[kt & 1][1][n], acc[m][n]);
    __builtin_amdgcn_s_setprio(0);
  }
#undef STAGE
#undef LOADBF

  // Epilogue: row = m0 + wm*64 + m*16 + q4*4 + r ; col = n0 + wn*64 + n*16 + c16
  const int crow = m0 + wm * 64 + q4 * 4;
  const int ccol = n0 + wn * 64 + c16;
  if constexpr (OUT == 0) {
    ushort* C = (ushort*)Cout;
#pragma unroll
    for (int m = 0; m < 4; ++m)
#pragma unroll
      for (int r = 0; r < 4; ++r) {
        ushort* cp = C + (size_t)(crow + m * 16 + r) * ldc + ccol;
        cp[0]  = f2bf(acc[m][0][r]);
        cp[16] = f2bf(acc[m][1][r]);
        cp[32] = f2bf(acc[m][2][r]);
        cp[48] = f2bf(acc[m][3][r]);
      }
  } else {
    float* C = (float*)Cout;
    const float b0 = bias[ccol], b1 = bias[ccol + 16];
    const float b2 = bias[ccol + 32], b3 = bias[ccol + 48];
#pragma unroll
    for (int m = 0; m < 4; ++m)
#pragma unroll
      for (int r = 0; r < 4; ++r) {
        float* cp = C + (size_t)win2orig((uint)(crow + m * 16 + r)) * 512 + ccol;
        cp[0]  = acc[m][0][r] + b0;
        cp[16] = acc[m][1][r] + b1;
        cp[32] = acc[m][2][r] + b2;
        cp[48] = acc[m][3][r] + b3;
      }
  }
}

// per-window attention (window-ordered qkv): one wave per (b, g, head).
// 2 waves/block (32 KB LDS); per-wave LDS only, no __syncthreads needed.
__global__ __launch_bounds__(128) void attn_win(const ushort* __restrict__ qkv,
                                                ushort* __restrict__ O) {
  __shared__ __align__(16) ushort p_lds[2][4096];
  __shared__ __align__(16) ushort v_lds[2][4096];
  const int tid = threadIdx.x, lane = tid & 63, w = tid >> 6;
  const int wg = blockIdx.x * 2 + w;
  const int head = wg & 7, g = (wg >> 3) & 63, b = wg >> 9;
  const int c16 = lane & 15, q4 = lane >> 4;
  const size_t wrow = (size_t)b * 3136 + g * 49;
  const u16x8 Z = {0, 0, 0, 0, 0, 0, 0, 0};

  const int qc = head * 64 + q4 * 8;
  u16x8 qf[2][4], kf[2][4];
#pragma unroll
  for (int i = 0; i < 4; ++i) {
    int s = i * 16 + c16;
    bool val = (s < 49);
    const ushort* p = qkv + (wrow + (val ? s : 0)) * 1536 + qc;
#pragma unroll
    for (int kk = 0; kk < 2; ++kk) {
      qf[kk][i] = val ? *reinterpret_cast<const u16x8*>(p + kk * 32) : Z;
      kf[kk][i] = val ? *reinterpret_cast<const u16x8*>(p + 512 + kk * 32) : Z;
    }
  }

  // stage V^T (XOR-swizzled): lane covers token t = lane
  {
    const ushort* vp = qkv + (wrow + (lane < 49 ? lane : 0)) * 1536 + 1024 + head * 64;
    u16x8 vr[8];
#pragma unroll
    for (int j = 0; j < 8; ++j)
      vr[j] = (lane < 49) ? *reinterpret_cast<const u16x8*>(vp + j * 8) : Z;
#pragma unroll
    for (int d = 0; d < 64; ++d)
      v_lds[w][(d * 64 + lane) ^ ((d & 7) << 3)] = vr[d >> 3][d & 7];
  }

  f32x4 acc[4][4];
#pragma unroll
  for (int m = 0; m < 4; ++m)
#pragma unroll
    for (int n = 0; n < 4; ++n) acc[m][n] = f32x4{0.f, 0.f, 0.f, 0.f};
  __builtin_amdgcn_s_setprio(1);
#pragma unroll
  for (int kk = 0; kk < 2; ++kk)
#pragma unroll
    for (int m = 0; m < 4; ++m)
#pragma unroll
      for (int n = 0; n < 4; ++n)
        acc[m][n] = mfma_bf16(qf[kk][m], kf[kk][n], acc[m][n]);
  __builtin_amdgcn_s_setprio(0);

#pragma unroll
  for (int m = 0; m < 4; ++m)
#pragma unroll
    for (int r = 0; r < 4; ++r) {
      float s0 = acc[m][0][r] * 0.125f;
      float s1 = acc[m][1][r] * 0.125f;
      float s2 = acc[m][2][r] * 0.125f;
      float s3 = (c16 == 0) ? acc[m][3][r] * 0.125f : -1e30f;
      float mx = fmaxf(fmaxf(s0, s1), fmaxf(s2, s3));
#pragma unroll
      for (int off = 1; off < 16; off <<= 1) mx = fmaxf(mx, __shfl_xor(mx, off));
      s0 = __expf(s0 - mx);
      s1 = __expf(s1 - mx);
      s2 = __expf(s2 - mx);
      s3 = (c16 == 0) ? __expf(s3 - mx) : 0.f;
      float sum = s0 + s1 + s2 + s3;
#pragma unroll
      for (int off = 1; off < 16; off <<= 1) sum += __shfl_xor(sum, off);
      float inv = 1.f / sum;
      int row = m * 16 + q4 * 4 + r;
      int rb = row * 64, swz = (row & 7) << 3;
      p_lds[w][(rb + c16) ^ swz]      = f2bf(s0 * inv);
      p_lds[w][(rb + 16 + c16) ^ swz] = f2bf(s1 * inv);
      p_lds[w][(rb + 32 + c16) ^ swz] = f2bf(s2 * inv);
      p_lds[w][(rb + 48 + c16) ^ swz] = f2bf(s3 * inv);
    }

  f32x4 o[4][4];
#pragma unroll
  for (int m = 0; m < 4; ++m)
#pragma unroll
    for (int n = 0; n < 4; ++n) o[m][n] = f32x4{0.f, 0.f, 0.f, 0.f};
#pragma unroll
  for (int kk = 0; kk < 2; ++kk) {
    u16x8 pa[4], vb[4];
#pragma unroll
    for (int m = 0; m < 4; ++m) {
      int row = m * 16 + c16;
      pa[m] = *reinterpret_cast<const u16x8*>(
          &p_lds[w][(row * 64 + kk * 32 + q4 * 8) ^ ((row & 7) << 3)]);
    }
#pragma unroll
    for (int n = 0; n < 4; ++n) {
      int d = n * 16 + c16;
      vb[n] = *reinterpret_cast<const u16x8*>(
          &v_lds[w][(d * 64 + kk * 32 + q4 * 8) ^ ((d & 7) << 3)]);
    }
    __builtin_amdgcn_s_setprio(1);
#pragma unroll
    for (int m = 0; m < 4; ++m)
#pragma unroll
      for (int n = 0; n < 4; ++n) o[m][n] = mfma_bf16(pa[m], vb[n], o[m][n]);
    __builtin_amdgcn_s_setprio(0);
  }

#pragma unroll
  for (int m = 0; m < 4; ++m)
#pragma unroll
    for (int r = 0; r < 4; ++r) {
      int s = m * 16 + q4 * 4 + r;
      if (s < 49) {
        ushort* op = O + (wrow + s) * 512 + head * 64 + c16;
        op[0]  = f2bf(o[m][0][r]);
        op[16] = f2bf(o[m][1][r]);
        op[32] = f2bf(o[m][2][r]);
        op[48] = f2bf(o[m][3][r]);
      }
    }
}

extern "C" void kernel_launch(void* const* d_in, const int* in_sizes, int n_in,
                              void* d_out, int out_size, void* d_ws, size_t ws_size,
                              hipStream_t stream) {
  const float* x      = (const float*)d_in[0];
  const float* w_qkv  = (const float*)d_in[1];
  const float* w_proj = (const float*)d_in[2];
  const float* b_proj = (const float*)d_in[3];
  char* ws = (char*)d_ws;
  ushort* wqkvT  = (ushort*)ws;                       // 1,572,864 B
  ushort* wprojT = (ushort*)(ws + 1572864);           //   524,288 B
  ushort* xb     = (ushort*)(ws + 2097152);           // 102,760,448 B (reused as attn out)
  ushort* qkv    = (ushort*)(ws + 104857600);         // 308,281,344 B
  float* out = (float*)d_out;

  transpose_cvt<<<dim3(48, 16), 256, 0, stream>>>(w_qkv, wqkvT, 512, 1536);
  transpose_cvt<<<dim3(16, 16), 256, 0, stream>>>(w_proj, wprojT, 512, 512);
  cvt_x_win<<<2048, 256, 0, stream>>>(x, xb, 100352 * 512 / 8);
  // GEMM1: 784 mtiles x 12 ntiles = 9408 blocks (1176/XCD)
  gemm_bl2<0><<<9408, 256, 0, stream>>>(xb, wqkvT, (void*)qkv, nullptr, 1536, 12, 1176);
  attn_win<<<8192, 128, 0, stream>>>(qkv, xb);
  // GEMM2: 784 x 4 = 3136 blocks (392/XCD), rows descattered to original order
  gemm_bl2<1><<<3136, 256, 0, stream>>>(xb, wprojT, (void*)out, b_proj, 512, 4, 392);
}

// Round 11
// 497.797 us; speedup vs baseline: 1.3102x; 1.3102x over previous
//
#include <hip/hip_runtime.h>

typedef unsigned short ushort;
typedef unsigned int uint;
typedef __bf16 bf16x8 __attribute__((ext_vector_type(8)));
typedef unsigned short u16x8 __attribute__((ext_vector_type(8)));
typedef float f32x4 __attribute__((ext_vector_type(4)));

__device__ __forceinline__ ushort f2bf(float f) {
  uint u = __builtin_bit_cast(uint, f);
  u += 0x7fffu + ((u >> 16) & 1u);
  return (ushort)(u >> 16);
}

__device__ __forceinline__ f32x4 mfma_bf16(u16x8 a, u16x8 b, f32x4 c) {
  return __builtin_amdgcn_mfma_f32_16x16x32_bf16(
      __builtin_bit_cast(bf16x8, a), __builtin_bit_cast(bf16x8, b), c, 0, 0, 0);
}

// window-ordered row -> original token row (B=32, H=W=56, ws=7)
__device__ __forceinline__ uint win2orig(uint wr) {
  uint b = wr / 3136u, rem = wr % 3136u;
  uint g = rem / 49u, s = rem % 49u;
  return b * 3136u + ((g >> 3) * 7u + s / 7u) * 56u + (g & 7u) * 7u + s % 7u;
}

// x fp32 (orig order) -> xb bf16 (window order), 8 elems/thread
__global__ __launch_bounds__(256) void cvt_x_win(const float* __restrict__ X,
                                                 ushort* __restrict__ Xb, int total8) {
  int stride = gridDim.x * 256;
  for (int i = blockIdx.x * 256 + threadIdx.x; i < total8; i += stride) {
    uint wr = (uint)i >> 6, c8 = (uint)i & 63u;
    const float* xp = X + (size_t)win2orig(wr) * 512 + c8 * 8;
    f32x4 a = *(const f32x4*)xp;
    f32x4 b = *(const f32x4*)(xp + 4);
    u16x8 o;
#pragma unroll
    for (int j = 0; j < 4; ++j) { o[j] = f2bf(a[j]); o[j + 4] = f2bf(b[j]); }
    ((u16x8*)Xb)[i] = o;
  }
}

// W[K=512][N] fp32 -> P[ng][kg][lane][8] bf16, MFMA-fragment-packed:
// P element (ng,kg,lane,e) = W[kg*32 + (lane>>4)*8 + e][ng*16 + (lane&15)].
// A wave's B-fragment load is then base + lane*16B -> fully coalesced 1 KB.
__global__ __launch_bounds__(256) void pack_w(const float* __restrict__ W,
                                              ushort* __restrict__ P,
                                              int N, int total) {
  int idx = blockIdx.x * 256 + threadIdx.x;  // one u16x8 per thread
  if (idx >= total) return;
  int lane = idx & 63;
  int fg = idx >> 6;      // ng*16 + kg   (K=512 -> 16 k-granules)
  int kg = fg & 15, ng = fg >> 4;
  int n = ng * 16 + (lane & 15);
  int k0 = kg * 32 + (lane >> 4) * 8;
  u16x8 o;
#pragma unroll
  for (int e = 0; e < 8; ++e) o[e] = f2bf(W[(size_t)(k0 + e) * N + n]);
  ((u16x8*)P)[idx] = o;
}

// ---- 128x128 GEMM, K=512: A via 3-buf LDS (48 KB, 2-deep prefetch),
// B direct from L2 in FRAGMENT-PACKED layout (coalesced 1 KB per load),
// double-banked in regs (1-deep prefetch). 4 waves, one barrier/K-step.
// vmcnt ledger (per wave, SCB-pinned issue order per iter:
//   STAGE(kt+2) [4 GLL] -> LOADBF(kt+1) [8 loads] -> MFMA(kt)):
// compiler's mandatory pre-MFMA(kt) wait for bf(kt) registers drains
// stage(kt+1) in FIFO order -> complete before BAR(kt+1), no explicit
// drain. WAR: stage(kt+2) overwrites buf[(kt+2)%3]; its last reads
// (iter kt-1) were lgkm-drained before MFMA(kt-1) < BAR(kt) < stage(kt+2).

#define GLL(g, l)                                                              \
  __builtin_amdgcn_global_load_lds(                                            \
      (const __attribute__((address_space(1))) uint*)(g),                      \
      (__attribute__((address_space(3))) uint*)(l), 16, 0, 0)
#define BAR() __builtin_amdgcn_s_barrier()
#define SCB() __builtin_amdgcn_sched_barrier(0)
#define WAITV(n) asm volatile("s_waitcnt vmcnt(" #n ")" ::: "memory")

template <int OUT>
__global__ __launch_bounds__(256, 3) void gemm_bl2(const ushort* __restrict__ A,
                                                   const ushort* __restrict__ BP,
                                                   void* __restrict__ Cout,
                                                   const float* __restrict__ bias,
                                                   const int ldc, const int NT,
                                                   const int CPX) {
  __shared__ __align__(16) ushort as_[3][8192];  // 3 x (128 x 64) bf16 = 48 KB
  const int bid = blockIdx.x;
  const int wg = (bid & 7) * CPX + (bid >> 3);  // XCD swizzle (grid % 8 == 0)
  const int mt = wg / NT, nt = wg - mt * NT;    // ntile-inner: B L2-resident
  const int m0 = mt << 7, n0 = nt << 7;
  const int tid = threadIdx.x, lane = tid & 63, wid = tid >> 6;
  const int wm = wid >> 1, wn = wid & 1;
  const int c16 = lane & 15, q4 = lane >> 4;
  const int sw = c16 & 7;

  // A staging source: thread t covers LDS slot (row=t>>3, gs=t&7); source
  // granule is gs ^ (row&7) so the read-side XOR recovers linear k.
  const ushort* Ag = A + (size_t)(m0 + (tid >> 3)) * 512 +
                     ((tid & 7) ^ ((tid >> 3) & 7)) * 8;
  // B fragment-packed base for this wave: ng_base = n0/16 + wn*4.
  // Fragment (n, kg) at Bp + (n*16 + kg)*512 (ushorts), lane-linear.
  const ushort* Bp = BP + ((size_t)((n0 >> 4) + wn * 4) * 16) * 512 + lane * 8;

  const int aro = wm * 64 + c16;         // af row base (+ f*16)
  const int ag0 = (q4 ^ sw) * 8;         // kk=0 granule slot
  const int ag1 = ((4 + q4) ^ sw) * 8;   // kk=1

  f32x4 acc[4][4];
#pragma unroll
  for (int m = 0; m < 4; ++m)
#pragma unroll
    for (int n = 0; n < 4; ++n) acc[m][n] = f32x4{0.f, 0.f, 0.f, 0.f};

  u16x8 bfr[2][2][4];  // [bank][kk][n]

#define STAGE(buf, ktg)                                                        \
  do {                                                                         \
    _Pragma("unroll") for (int j_ = 0; j_ < 4; ++j_)                           \
        GLL(Ag + (size_t)j_ * (32 * 512) + (ktg)*64,                           \
            &as_[buf][j_ * 2048 + tid * 8]);                                   \
  } while (0)
#define LOADBF(bank, ktg)                                                      \
  do {                                                                         \
    _Pragma("unroll") for (int kk_ = 0; kk_ < 2; ++kk_)                        \
        _Pragma("unroll") for (int n_ = 0; n_ < 4; ++n_)                       \
            bfr[bank][kk_][n_] =                                               \
        *(const u16x8*)(Bp + (size_t)(n_ * 16 + (ktg)*2 + kk_) * 512);         \
  } while (0)

  // Prologue: A(0)->buf0, A(1)->buf1, bf(0)->bank0.
  STAGE(0, 0);
  SCB();
  LOADBF(0, 0);
  SCB();
  STAGE(1, 1);
  WAITV(12);  // outstanding 16: drain stage(0) (oldest 4)

#pragma unroll
  for (int kt = 0; kt < 8; ++kt) {
    BAR();
    SCB();
    if (kt < 6) STAGE((kt + 2) % 3, kt + 2);
    SCB();  // pin: stage(kt+2) issues before bf(kt+1)
    if (kt < 7) LOADBF((kt + 1) & 1, kt + 1);
    SCB();  // pin: bf loads issue before af ds_reads / MFMA
    const ushort* ab = &as_[kt % 3][0];
    u16x8 af0[4];
#pragma unroll
    for (int f = 0; f < 4; ++f)
      af0[f] = *(const u16x8*)(ab + (aro + f * 16) * 64 + ag0);
    __builtin_amdgcn_s_setprio(1);
#pragma unroll
    for (int m = 0; m < 4; ++m)
#pragma unroll
      for (int n = 0; n < 4; ++n)
        acc[m][n] = mfma_bf16(af0[m], bfr[kt & 1][0][n], acc[m][n]);
    __builtin_amdgcn_s_setprio(0);
    u16x8 af1[4];
#pragma unroll
    for (int f = 0; f < 4; ++f)
      af1[f] = *(const u16x8*)(ab + (aro + f * 16) * 64 + ag1);
    __builtin_amdgcn_s_setprio(1);
#pragma unroll
    for (int m = 0; m < 4; ++m)
#pragma unroll
      for (int n = 0; n < 4; ++n)
        acc[m][n] = mfma_bf16(af1[m], bfr[kt & 1][1][n], acc[m][n]);
    __builtin_amdgcn_s_setprio(0);
  }
#undef STAGE
#undef LOADBF

  // Epilogue: row = m0 + wm*64 + m*16 + q4*4 + r ; col = n0 + wn*64 + n*16 + c16
  const int crow = m0 + wm * 64 + q4 * 4;
  const int ccol = n0 + wn * 64 + c16;
  if constexpr (OUT == 0) {
    ushort* C = (ushort*)Cout;
#pragma unroll
    for (int m = 0; m < 4; ++m)
#pragma unroll
      for (int r = 0; r < 4; ++r) {
        ushort* cp = C + (size_t)(crow + m * 16 + r) * ldc + ccol;
        cp[0]  = f2bf(acc[m][0][r]);
        cp[16] = f2bf(acc[m][1][r]);
        cp[32] = f2bf(acc[m][2][r]);
        cp[48] = f2bf(acc[m][3][r]);
      }
  } else {
    float* C = (float*)Cout;
    const float b0 = bias[ccol], b1 = bias[ccol + 16];
    const float b2 = bias[ccol + 32], b3 = bias[ccol + 48];
#pragma unroll
    for (int m = 0; m < 4; ++m)
#pragma unroll
      for (int r = 0; r < 4; ++r) {
        float* cp = C + (size_t)win2orig((uint)(crow + m * 16 + r)) * 512 + ccol;
        cp[0]  = acc[m][0][r] + b0;
        cp[16] = acc[m][1][r] + b1;
        cp[32] = acc[m][2][r] + b2;
        cp[48] = acc[m][3][r] + b3;
      }
  }
}

// per-window attention (window-ordered qkv): one wave per (b, g, head).
// 2 waves/block (32 KB LDS); per-wave LDS only, no __syncthreads needed.
__global__ __launch_bounds__(128) void attn_win(const ushort* __restrict__ qkv,
                                                ushort* __restrict__ O) {
  __shared__ __align__(16) ushort p_lds[2][4096];
  __shared__ __align__(16) ushort v_lds[2][4096];
  const int tid = threadIdx.x, lane = tid & 63, w = tid >> 6;
  const int wg = blockIdx.x * 2 + w;
  const int head = wg & 7, g = (wg >> 3) & 63, b = wg >> 9;
  const int c16 = lane & 15, q4 = lane >> 4;
  const size_t wrow = (size_t)b * 3136 + g * 49;
  const u16x8 Z = {0, 0, 0, 0, 0, 0, 0, 0};

  const int qc = head * 64 + q4 * 8;
  u16x8 qf[2][4], kf[2][4];
#pragma unroll
  for (int i = 0; i < 4; ++i) {
    int s = i * 16 + c16;
    bool val = (s < 49);
    const ushort* p = qkv + (wrow + (val ? s : 0)) * 1536 + qc;
#pragma unroll
    for (int kk = 0; kk < 2; ++kk) {
      qf[kk][i] = val ? *reinterpret_cast<const u16x8*>(p + kk * 32) : Z;
      kf[kk][i] = val ? *reinterpret_cast<const u16x8*>(p + 512 + kk * 32) : Z;
    }
  }

  // stage V^T (XOR-swizzled): lane covers token t = lane
  {
    const ushort* vp = qkv + (wrow + (lane < 49 ? lane : 0)) * 1536 + 1024 + head * 64;
    u16x8 vr[8];
#pragma unroll
    for (int j = 0; j < 8; ++j)
      vr[j] = (lane < 49) ? *reinterpret_cast<const u16x8*>(vp + j * 8) : Z;
#pragma unroll
    for (int d = 0; d < 64; ++d)
      v_lds[w][(d * 64 + lane) ^ ((d & 7) << 3)] = vr[d >> 3][d & 7];
  }

  f32x4 acc[4][4];
#pragma unroll
  for (int m = 0; m < 4; ++m)
#pragma unroll
    for (int n = 0; n < 4; ++n) acc[m][n] = f32x4{0.f, 0.f, 0.f, 0.f};
  __builtin_amdgcn_s_setprio(1);
#pragma unroll
  for (int kk = 0; kk < 2; ++kk)
#pragma unroll
    for (int m = 0; m < 4; ++m)
#pragma unroll
      for (int n = 0; n < 4; ++n)
        acc[m][n] = mfma_bf16(qf[kk][m], kf[kk][n], acc[m][n]);
  __builtin_amdgcn_s_setprio(0);

#pragma unroll
  for (int m = 0; m < 4; ++m)
#pragma unroll
    for (int r = 0; r < 4; ++r) {
      float s0 = acc[m][0][r] * 0.125f;
      float s1 = acc[m][1][r] * 0.125f;
      float s2 = acc[m][2][r] * 0.125f;
      float s3 = (c16 == 0) ? acc[m][3][r] * 0.125f : -1e30f;
      float mx = fmaxf(fmaxf(s0, s1), fmaxf(s2, s3));
#pragma unroll
      for (int off = 1; off < 16; off <<= 1) mx = fmaxf(mx, __shfl_xor(mx, off));
      s0 = __expf(s0 - mx);
      s1 = __expf(s1 - mx);
      s2 = __expf(s2 - mx);
      s3 = (c16 == 0) ? __expf(s3 - mx) : 0.f;
      float sum = s0 + s1 + s2 + s3;
#pragma unroll
      for (int off = 1; off < 16; off <<= 1) sum += __shfl_xor(sum, off);
      float inv = 1.f / sum;
      int row = m * 16 + q4 * 4 + r;
      int rb = row * 64, swz = (row & 7) << 3;
      p_lds[w][(rb + c16) ^ swz]      = f2bf(s0 * inv);
      p_lds[w][(rb + 16 + c16) ^ swz] = f2bf(s1 * inv);
      p_lds[w][(rb + 32 + c16) ^ swz] = f2bf(s2 * inv);
      p_lds[w][(rb + 48 + c16) ^ swz] = f2bf(s3 * inv);
    }

  f32x4 o[4][4];
#pragma unroll
  for (int m = 0; m < 4; ++m)
#pragma unroll
    for (int n = 0; n < 4; ++n) o[m][n] = f32x4{0.f, 0.f, 0.f, 0.f};
#pragma unroll
  for (int kk = 0; kk < 2; ++kk) {
    u16x8 pa[4], vb[4];
#pragma unroll
    for (int m = 0; m < 4; ++m) {
      int row = m * 16 + c16;
      pa[m] = *reinterpret_cast<const u16x8*>(
          &p_lds[w][(row * 64 + kk * 32 + q4 * 8) ^ ((row & 7) << 3)]);
    }
#pragma unroll
    for (int n = 0; n < 4; ++n) {
      int d = n * 16 + c16;
      vb[n] = *reinterpret_cast<const u16x8*>(
          &v_lds[w][(d * 64 + kk * 32 + q4 * 8) ^ ((d & 7) << 3)]);
    }
    __builtin_amdgcn_s_setprio(1);
#pragma unroll
    for (int m = 0; m < 4; ++m)
#pragma unroll
      for (int n = 0; n < 4; ++n) o[m][n] = mfma_bf16(pa[m], vb[n], o[m][n]);
    __builtin_amdgcn_s_setprio(0);
  }

#pragma unroll
  for (int m = 0; m < 4; ++m)
#pragma unroll
    for (int r = 0; r < 4; ++r) {
      int s = m * 16 + q4 * 4 + r;
      if (s < 49) {
        ushort* op = O + (wrow + s) * 512 + head * 64 + c16;
        op[0]  = f2bf(o[m][0][r]);
        op[16] = f2bf(o[m][1][r]);
        op[32] = f2bf(o[m][2][r]);
        op[48] = f2bf(o[m][3][r]);
      }
    }
}

extern "C" void kernel_launch(void* const* d_in, const int* in_sizes, int n_in,
                              void* d_out, int out_size, void* d_ws, size_t ws_size,
                              hipStream_t stream) {
  const float* x      = (const float*)d_in[0];
  const float* w_qkv  = (const float*)d_in[1];
  const float* w_proj = (const float*)d_in[2];
  const float* b_proj = (const float*)d_in[3];
  char* ws = (char*)d_ws;
  ushort* wqkvP  = (ushort*)ws;                       // 1,572,864 B (frag-packed)
  ushort* wprojP = (ushort*)(ws + 1572864);           //   524,288 B (frag-packed)
  ushort* xb     = (ushort*)(ws + 2097152);           // 102,760,448 B (reused as attn out)
  ushort* qkv    = (ushort*)(ws + 104857600);         // 308,281,344 B
  float* out = (float*)d_out;

  pack_w<<<384, 256, 0, stream>>>(w_qkv, wqkvP, 1536, 1536 * 512 / 8);
  pack_w<<<128, 256, 0, stream>>>(w_proj, wprojP, 512, 512 * 512 / 8);
  cvt_x_win<<<2048, 256, 0, stream>>>(x, xb, 100352 * 512 / 8);
  // GEMM1: 784 mtiles x 12 ntiles = 9408 blocks (1176/XCD)
  gemm_bl2<0><<<9408, 256, 0, stream>>>(xb, wqkvP, (void*)qkv, nullptr, 1536, 12, 1176);
  attn_win<<<8192, 128, 0, stream>>>(qkv, xb);
  // GEMM2: 784 x 4 = 3136 blocks (392/XCD), rows descattered to original order
  gemm_bl2<1><<<3136, 256, 0, stream>>>(xb, wprojP, (void*)out, b_proj, 512, 4, 392);
}